// Round 10
// baseline (1790.851 us; speedup 1.0000x reference)
//
#include <hip/hip_runtime.h>
#include <hip/hip_bf16.h>
#include <math.h>

#define KIMG 8
#define HH 128
#define WW 128
#define NTOK (HH*WW)
#define DD 768
#define CC 10
#define NITER 5
#define GA 32          // assign blocks per image (256 total = 1/CU)
#define TG 32          // sum tokgroups per image
#define WVS 8          // waves per block (512 threads)
#define NWV (GA*WVS)   // 256 waves per image

// ---------- wave helpers ----------
__device__ __forceinline__ float rl_f(float x, int l){
  return __int_as_float(__builtin_amdgcn_readlane(__float_as_int(x), l));
}
__device__ __forceinline__ float rfl_f(float x){
  return __int_as_float(__builtin_amdgcn_readfirstlane(__float_as_int(x)));
}
template<int CTRL,int RMASK>
__device__ __forceinline__ float dppadd(float x){
  // compiler-managed DPP (hazard-safe): mov_dpp + add
  int y = __builtin_amdgcn_update_dpp(0, __float_as_int(x), CTRL, RMASK, 0xf, true);
  return x + __int_as_float(y);
}
// sum across a 4-lane quad; result identical in all 4 lanes
__device__ __forceinline__ float quadred(float x){
  x = dppadd<0xB1,0xf>(x);   // quad_perm [1,0,3,2]
  x = dppadd<0x4E,0xf>(x);   // quad_perm [2,3,0,1]
  return x;
}
// full-wave sum; total lands in lane 63
__device__ __forceinline__ float wredsum(float x){
  x = dppadd<0x111,0xf>(x);
  x = dppadd<0x112,0xf>(x);
  x = dppadd<0x114,0xf>(x);
  x = dppadd<0x118,0xf>(x);
  x = dppadd<0x142,0xa>(x);
  x = dppadd<0x143,0xc>(x);
  return x;
}
__device__ __forceinline__ float read_dim_f(const int* p){
  int v = *p;
  if (v > 0 && v < (1<<20)) return (float)v;   // plausible integer
  return __int_as_float(v);                    // else float bits
}

union F4 { float4 v; float f[4]; };

// ---------- 1. compact valid token indices (deterministic order) ----------
__global__ __launch_bounds__(256) void compact_kernel(const float* __restrict__ mask,
    int* __restrict__ vidx, int* __restrict__ vcnt){
  int k = blockIdx.x, tid = threadIdx.x;
  __shared__ int s[256];
  const float* mk = mask + (size_t)k*NTOK;
  int base = tid*64, c = 0;
  for (int j=0;j<64;j++) c += (mk[base+j] > 0.f) ? 1 : 0;
  s[tid] = c; __syncthreads();
  for (int st=1; st<256; st<<=1){
    int v = s[tid]; int u = (tid>=st) ? s[tid-st] : 0;
    __syncthreads(); s[tid] = v+u; __syncthreads();
  }
  int off = s[tid] - c;          // exclusive prefix
  if (tid==255) vcnt[k] = s[255];
  int* vk = vidx + (size_t)k*NTOK;
  for (int j=0;j<64;j++){ if (mk[base+j] > 0.f) vk[off++] = base+j; }
}

// ---------- 2. initial centroids = tokens[init_idx] ----------
__global__ __launch_bounds__(256) void init_kernel(const float* __restrict__ feat,
  const float* __restrict__ boxes, const float* __restrict__ Wp, const float* __restrict__ bp,
  const int* __restrict__ iidx, const int* __restrict__ prawh, const int* __restrict__ praww,
  float* __restrict__ cent){
  int k = blockIdx.x, tid = threadIdx.x;
  float top = boxes[k*4+0], lft = boxes[k*4+1], bot = boxes[k*4+2], rgt = boxes[k*4+3];
  float rh = read_dim_f(prawh), rw = read_dim_f(praww);
  float inv_rw = 1.f/(rw-1.f), inv_rh = 1.f/(rh-1.f);
  float xs = (rgt-lft)*(1.f/(float)WW), ys = (bot-top)*(1.f/(float)HH);
  for (int c=0;c<CC;c++){
    int tok = iidx[k*CC+c];
    int h = tok>>7, w = tok&127;
    float xg = fminf(fmaxf(((float)w*xs+lft)*inv_rw,0.f),1.f);
    float yg = fminf(fmaxf(((float)h*ys+top)*inv_rh,0.f),1.f);
    const float* fp = feat + ((size_t)k*NTOK + tok)*DD;
    float* cp = cent + ((size_t)k*CC + c)*DD;
    for (int d=tid; d<DD; d+=256)
      cp[d] = fp[d] + xg*Wp[d] + yg*Wp[DD+d] + bp[d];
  }
}

// ---------- 2b. initial per-cluster scalars (used once, before iter 0) ----------
__global__ __launch_bounds__(64) void scalar_kernel(const float* __restrict__ cent,
  const float* __restrict__ Wp, const float* __restrict__ bp, float* __restrict__ scal){
  int c = blockIdx.x, k = blockIdx.y, lane = threadIdx.x;
  const float* cp = cent + ((size_t)k*CC+c)*DD;
  float a0=0.f,a1=0.f,ab=0.f,an=0.f;
  #pragma unroll
  for (int j=0;j<12;j++){
    float cv = cp[j*64+lane];
    a0=fmaf(cv,Wp[j*64+lane],a0);
    a1=fmaf(cv,Wp[DD+j*64+lane],a1);
    ab=fmaf(cv,bp[j*64+lane],ab);
    an=fmaf(cv,cv,an);
  }
  a0=wredsum(a0); a1=wredsum(a1); ab=wredsum(ab); an=wredsum(an);
  if (lane==63){
    float* o = scal + ((size_t)k*CC+c)*4;
    o[0]=fmaf(-2.f,ab,an); o[1]=-2.f*a0; o[2]=-2.f*a1; o[3]=0.f;
  }
}

// ---------- 3a. LABELS: streaming dot phase, deep-pipelined ----------
// Quad-owns-token; wave handles 3 segments of 16 tokens (segments w, w+256,
// w+512 of the compact list). 4-chunk-deep manual buffer rotation (bufA..D)
// keeps ~12 b128 loads in flight per wave. No LDS atomics anywhere.
__global__ __launch_bounds__(512,2) void assign_kernel(
    const float* __restrict__ feat, const float* __restrict__ boxes,
    const int* __restrict__ prawh, const int* __restrict__ praww,
    const float* __restrict__ cent, const float* __restrict__ scal,
    const int* __restrict__ vidx, const int* __restrict__ vcnt,
    int* __restrict__ labels, float* __restrict__ osxg, float* __restrict__ osyg,
    float* __restrict__ ocnt)
{
  int g = blockIdx.x, k = blockIdx.y;
  int tid = threadIdx.x, lane = tid & 63, wv = tid >> 6;
  __shared__ float s_cent[CC*DD];           // -2 * centroids
  const float* ck = cent + (size_t)k*CC*DD;
  for (int x=tid;x<CC*DD;x+=512) s_cent[x] = -2.f*ck[x];
  __syncthreads();

  // per-cluster scalars -> SGPRs (wave-uniform)
  float sA[CC], sW0[CC], sW1[CC];
  #pragma unroll
  for (int c=0;c<CC;c++){
    F4 sv; sv.v = *(const float4*)(scal + ((size_t)k*CC+c)*4);
    sA[c]=rfl_f(sv.f[0]); sW0[c]=rfl_f(sv.f[1]); sW1[c]=rfl_f(sv.f[2]);
  }

  float top=rfl_f(boxes[k*4+0]), lft=rfl_f(boxes[k*4+1]);
  float bot=rfl_f(boxes[k*4+2]), rgt=rfl_f(boxes[k*4+3]);
  float rh = read_dim_f(prawh), rw = read_dim_f(praww);
  float inv_rw = 1.f/(rw-1.f), inv_rh = 1.f/(rh-1.f);
  float xs = (rgt-lft)*(1.f/(float)WW), ys = (bot-top)*(1.f/(float)HH);

  int count = vcnt[k];
  int wid = g*WVS + wv;                     // 0..255
  const int* vk = vidx + (size_t)k*NTOK;
  const float* featk = feat + (size_t)k*NTOK*DD;
  int* lk = labels + (size_t)k*NTOK;
  int c1 = count - 1;

  int q  = lane >> 2;                       // token slot within segment
  int r4 = lane & 3;                        // dim part

  // 3 segments per wave: positions (wid + b*256)*16 + q
  int base3[3]; const float* rb[3]; float xg[3], yg[3];
  #pragma unroll
  for (int b=0;b<3;b++){
    base3[b] = (wid + b*256)*16;
    int t = vk[min(base3[b]+q, c1)];
    rb[b] = featk + (size_t)t*DD + r4*4;
    xg[b] = fminf(fmaxf(((float)(t&127)*xs+lft)*inv_rw,0.f),1.f);
    yg[b] = fminf(fmaxf(((float)(t>>7) *ys+top)*inv_rh,0.f),1.f);
  }

  float acc[3][CC];
  #pragma unroll
  for (int b=0;b<3;b++)
    #pragma unroll
    for (int c=0;c<CC;c++) acc[b][c]=0.f;

  auto refill = [&](F4* buf, int ch){
    #pragma unroll
    for (int b=0;b<3;b++) buf[b].v = *(const float4*)(rb[b] + ch*16);
  };
  auto fmachunk = [&](F4* buf, int ch){
    #pragma unroll
    for (int c=0;c<CC;c++){
      F4 cs; cs.v = *(const float4*)(s_cent + c*DD + ch*16 + r4*4);
      #pragma unroll
      for (int b=0;b<3;b++)
        #pragma unroll
        for (int m=0;m<4;m++)
          acc[b][c] = fmaf(buf[b].f[m], cs.f[m], acc[b][c]);
    }
  };

  F4 bA[3], bB[3], bC[3], bD[3];
  refill(bA,0); refill(bB,1); refill(bC,2); refill(bD,3);
  for (int ch=0; ch<48; ch+=4){
    fmachunk(bA, ch  ); if (ch+4<48) refill(bA, ch+4);
    fmachunk(bB, ch+1); if (ch+5<48) refill(bB, ch+5);
    fmachunk(bC, ch+2); if (ch+6<48) refill(bC, ch+6);
    fmachunk(bD, ch+3); if (ch+7<48) refill(bD, ch+7);
  }

  // quad butterfly + per-token argmin
  int bl[3];
  #pragma unroll
  for (int b=0;b<3;b++){
    float best=3.4e38f; int bb=0;
    #pragma unroll
    for (int c=0;c<CC;c++){
      float d = quadred(acc[b][c]);         // = -2*(t.c), same in all 4 quad lanes
      float sc = fmaf(xg[b],sW0[c], fmaf(yg[b],sW1[c], sA[c])) + d;
      if (sc < best){ best=sc; bb=c; }
    }
    bl[b]=bb;
  }

  // plain label stores (lane r4==0 per quad), guarded to real positions
  #pragma unroll
  for (int b=0;b<3;b++){
    int pos = base3[b] + q;
    if (r4==0 && pos < count) lk[pos] = bl[b];
  }

  // register aux accumulate (each token counted by its 4 quad lanes -> *0.25)
  float axc[CC], axx[CC], axy[CC];
  #pragma unroll
  for (int c=0;c<CC;c++){ axc[c]=0.f; axx[c]=0.f; axy[c]=0.f; }
  #pragma unroll
  for (int b=0;b<3;b++){
    bool val = (base3[b] + q) < count;
    #pragma unroll
    for (int c=0;c<CC;c++){
      bool mm = val && (bl[b]==c);
      axc[c] += mm ? 1.f   : 0.f;
      axx[c] += mm ? xg[b] : 0.f;
      axy[c] += mm ? yg[b] : 0.f;
    }
  }
  #pragma unroll
  for (int c=0;c<CC;c++){
    axc[c]=wredsum(axc[c]); axx[c]=wredsum(axx[c]); axy[c]=wredsum(axy[c]);
  }
  if (lane==63){
    size_t o = ((size_t)k*NWV + wid)*CC;
    #pragma unroll
    for (int c=0;c<CC;c++){
      ocnt[o+c]=0.25f*axc[c]; osxg[o+c]=0.25f*axx[c]; osyg[o+c]=0.25f*axy[c];
    }
  }
}

// ---------- 3b. SUMS: label-gathered dim-slice accumulation, NO atomics ----------
// Lane owns 4 dims of a 256-dim slice. Uniform label -> scalar switch; only
// the matching cluster's 4 adds execute (~30cy/token vs 120 for cndmask).
// Depth-3 load rotation; two-phase LDS reduce (40 KiB -> 3 blocks/CU).
__global__ __launch_bounds__(512,4) void sum_kernel(
    const float* __restrict__ feat, const int* __restrict__ vidx,
    const int* __restrict__ vcnt, const int* __restrict__ labels,
    float* __restrict__ fsums)
{
  int tg = blockIdx.x, sl = blockIdx.y, k = blockIdx.z;
  int tid = threadIdx.x, lane = tid & 63, wv = tid >> 6;
  __shared__ float s_red[4][CC*256];        // 40 KiB
  int count = vcnt[k];
  int wid = tg*WVS + wv;                    // 0..255
  int wbeg = (int)(((long long)count * wid) / NWV);
  int wend = (int)(((long long)count * (wid+1)) / NWV);
  int mycnt = wend - wbeg;                  // <= 64
  const float* featk = feat + (size_t)k*NTOK*DD + sl*256;
  const int* vk = vidx + (size_t)k*NTOK;
  const int* lk = labels + (size_t)k*NTOK;

  float acc[CC][4];
  #pragma unroll
  for (int c=0;c<CC;c++)
    #pragma unroll
    for (int j=0;j<4;j++) acc[c][j]=0.f;

  if (mycnt > 0){
    int c1 = count - 1;
    int vvt = vk[min(wbeg + lane, c1)];     // lane-held token ids
    int vlb = lk[min(wbeg + lane, c1)];     // lane-held labels (compact pos)

    auto addr = [&](int t)->const float*{
      int tok = __builtin_amdgcn_readlane(vvt, min(t, mycnt-1));
      return featk + (size_t)tok*DD + lane*4;
    };
    auto consume = [&](F4& v, int t){
      int lbl = __builtin_amdgcn_readlane(vlb, t);   // SGPR -> scalar branch
      switch(lbl){
        case 0: acc[0][0]+=v.f[0]; acc[0][1]+=v.f[1]; acc[0][2]+=v.f[2]; acc[0][3]+=v.f[3]; break;
        case 1: acc[1][0]+=v.f[0]; acc[1][1]+=v.f[1]; acc[1][2]+=v.f[2]; acc[1][3]+=v.f[3]; break;
        case 2: acc[2][0]+=v.f[0]; acc[2][1]+=v.f[1]; acc[2][2]+=v.f[2]; acc[2][3]+=v.f[3]; break;
        case 3: acc[3][0]+=v.f[0]; acc[3][1]+=v.f[1]; acc[3][2]+=v.f[2]; acc[3][3]+=v.f[3]; break;
        case 4: acc[4][0]+=v.f[0]; acc[4][1]+=v.f[1]; acc[4][2]+=v.f[2]; acc[4][3]+=v.f[3]; break;
        case 5: acc[5][0]+=v.f[0]; acc[5][1]+=v.f[1]; acc[5][2]+=v.f[2]; acc[5][3]+=v.f[3]; break;
        case 6: acc[6][0]+=v.f[0]; acc[6][1]+=v.f[1]; acc[6][2]+=v.f[2]; acc[6][3]+=v.f[3]; break;
        case 7: acc[7][0]+=v.f[0]; acc[7][1]+=v.f[1]; acc[7][2]+=v.f[2]; acc[7][3]+=v.f[3]; break;
        case 8: acc[8][0]+=v.f[0]; acc[8][1]+=v.f[1]; acc[8][2]+=v.f[2]; acc[8][3]+=v.f[3]; break;
        default: acc[9][0]+=v.f[0]; acc[9][1]+=v.f[1]; acc[9][2]+=v.f[2]; acc[9][3]+=v.f[3]; break;
      }
    };

    F4 b0,b1,b2;
    b0.v = *(const float4*)addr(0);
    b1.v = *(const float4*)addr(1);
    b2.v = *(const float4*)addr(2);
    for (int t=0; t<mycnt; t+=3){
      consume(b0, t);
      if (t+3 < mycnt) b0.v = *(const float4*)addr(t+3);
      if (t+1 < mycnt){
        consume(b1, t+1);
        if (t+4 < mycnt) b1.v = *(const float4*)addr(t+4);
      }
      if (t+2 < mycnt){
        consume(b2, t+2);
        if (t+5 < mycnt) b2.v = *(const float4*)addr(t+5);
      }
    }
  }

  // two-phase deterministic reduce: (w, w+4) pairs, then 0..3 in order
  if (wv >= 4){
    float* dst = &s_red[wv-4][0];
    #pragma unroll
    for (int c=0;c<CC;c++){
      F4 u; u.f[0]=acc[c][0]; u.f[1]=acc[c][1]; u.f[2]=acc[c][2]; u.f[3]=acc[c][3];
      *(float4*)(dst + c*256 + lane*4) = u.v;
    }
  }
  __syncthreads();
  if (wv < 4){
    float* src = &s_red[wv][0];
    #pragma unroll
    for (int c=0;c<CC;c++){
      F4 u; u.v = *(const float4*)(src + c*256 + lane*4);
      #pragma unroll
      for (int j=0;j<4;j++) acc[c][j] += u.f[j];
    }
    #pragma unroll
    for (int c=0;c<CC;c++){
      F4 u; u.f[0]=acc[c][0]; u.f[1]=acc[c][1]; u.f[2]=acc[c][2]; u.f[3]=acc[c][3];
      *(float4*)(src + c*256 + lane*4) = u.v;
    }
  }
  __syncthreads();
  for (int x=tid; x<CC*256; x+=512){
    float s = ((s_red[0][x] + s_red[1][x]) + s_red[2][x]) + s_red[3][x];
    int c = x >> 8, dm = x & 255;
    fsums[(((size_t)k*TG + tg)*CC + c)*DD + sl*256 + dm] = s;
  }
}

// ---------- 4. centroid update + fused scalar recompute ----------
// One block per (k,c); thread owns dims d, d+256, d+512.
__global__ __launch_bounds__(256) void update_kernel(
  const float* __restrict__ fsums, const float* __restrict__ osxg, const float* __restrict__ osyg,
  const float* __restrict__ ocnt, const float* __restrict__ Wp, const float* __restrict__ bp,
  float* __restrict__ cent, float* __restrict__ scal)
{
  int kc = blockIdx.x; int k = kc/CC, c = kc - k*CC;
  int tid = threadIdx.x, lane = tid & 63, wv = tid >> 6;
  __shared__ float rn[4], rx[4], ry[4];
  __shared__ float s0[4], s1[4], s2[4], s3[4];

  // aux reduce over 256 wave slots
  size_t o = ((size_t)k*NWV + tid)*CC + c;
  float pn = ocnt[o], px = osxg[o], py = osyg[o];
  float wn = wredsum(pn), wx = wredsum(px), wy = wredsum(py);
  if (lane==63){ rn[wv]=wn; rx[wv]=wx; ry[wv]=wy; }
  __syncthreads();
  float n  = rn[0]+rn[1]+rn[2]+rn[3];
  float sx = rx[0]+rx[1]+rx[2]+rx[3];
  float sy = ry[0]+ry[1]+ry[2]+ry[3];
  bool upd = (n > 0.5f);

  float a0=0.f, a1=0.f, ab=0.f, an2=0.f;
  #pragma unroll
  for (int p=0;p<3;p++){
    int d = p*256 + tid;
    float s = 0.f;
    for (int g2=0; g2<TG; g2++)
      s += fsums[(((size_t)k*TG + g2)*CC + c)*DD + d];
    float w0 = Wp[d], w1 = Wp[DD+d], bb = bp[d];
    float val;
    if (upd) val = (s + sx*w0 + sy*w1 + n*bb) / n;     // factored posenc re-applied
    else     val = cent[(size_t)kc*DD + d];            // keep old centroid
    cent[(size_t)kc*DD + d] = val;
    a0  = fmaf(val, w0, a0);
    a1  = fmaf(val, w1, a1);
    ab  = fmaf(val, bb, ab);
    an2 = fmaf(val, val, an2);
  }
  a0=wredsum(a0); a1=wredsum(a1); ab=wredsum(ab); an2=wredsum(an2);
  if (lane==63){ s0[wv]=a0; s1[wv]=a1; s2[wv]=ab; s3[wv]=an2; }
  __syncthreads();
  if (tid==0){
    float A0 = s0[0]+s0[1]+s0[2]+s0[3];
    float A1 = s1[0]+s1[1]+s1[2]+s1[3];
    float AB = s2[0]+s2[1]+s2[2]+s2[3];
    float AN = s3[0]+s3[1]+s3[2]+s3[3];
    float* op = scal + (size_t)kc*4;
    op[0]=fmaf(-2.f,AB,AN); op[1]=-2.f*A0; op[2]=-2.f*A1; op[3]=0.f;
  }
}

// ---------- 5. MLP ----------
__global__ __launch_bounds__(256) void mlp1_kernel(const float* __restrict__ cent,
  const float* __restrict__ W1, const float* __restrict__ b1, float* __restrict__ h1)
{
  int k = blockIdx.y; int col = blockIdx.x*256 + threadIdx.x;
  __shared__ float srow[CC*DD];
  for (int x=threadIdx.x; x<CC*DD; x+=256) srow[x] = cent[(size_t)k*CC*DD + x];
  __syncthreads();
  float acc[CC];
  #pragma unroll
  for (int r=0;r<CC;r++) acc[r]=0.f;
  for (int dd=0; dd<DD; dd++){
    float wv = W1[(size_t)dd*DD + col];
    #pragma unroll
    for (int r=0;r<CC;r++) acc[r] = fmaf(srow[r*DD+dd], wv, acc[r]);
  }
  float bb = b1[col];
  #pragma unroll
  for (int r=0;r<CC;r++){
    float x = acc[r] + bb;
    h1[((size_t)k*CC+r)*DD + col] = 0.5f*x*(1.f+erff(x*0.70710678118654752440f));
  }
}

__global__ __launch_bounds__(256) void mlp2_kernel(const float* __restrict__ h1,
  const float* __restrict__ W2, const float* __restrict__ b2, float* __restrict__ out)
{
  int k = blockIdx.y; int col = blockIdx.x*256 + threadIdx.x;
  __shared__ float srow[CC*DD];
  for (int x=threadIdx.x; x<CC*DD; x+=256) srow[x] = h1[(size_t)k*CC*DD + x];
  __syncthreads();
  float acc[CC];
  #pragma unroll
  for (int r=0;r<CC;r++) acc[r]=0.f;
  for (int dd=0; dd<DD; dd++){
    float wv = W2[(size_t)dd*DD + col];
    #pragma unroll
    for (int r=0;r<CC;r++) acc[r] = fmaf(srow[r*DD+dd], wv, acc[r]);
  }
  float bb2 = b2[col];
  #pragma unroll
  for (int r=0;r<CC;r++) out[((size_t)k*CC+r)*DD + col] = acc[r] + bb2;
}

// ---------- launch ----------
extern "C" void kernel_launch(void* const* d_in, const int* in_sizes, int n_in,
                              void* d_out, int out_size, void* d_ws, size_t ws_size,
                              hipStream_t stream)
{
  const float* feat = (const float*)d_in[0];
  const float* mask = (const float*)d_in[1];
  const float* boxes= (const float*)d_in[2];
  const float* Wp   = (const float*)d_in[3];
  const float* bp   = (const float*)d_in[4];
  const float* W1   = (const float*)d_in[5];
  const float* b1   = (const float*)d_in[6];
  const float* W2   = (const float*)d_in[7];
  const float* b2   = (const float*)d_in[8];
  const int*   iidx = (const int*)d_in[9];
  const int*   prawh= (const int*)d_in[10];
  const int*   praww= (const int*)d_in[11];
  float* out = (float*)d_out;

  auto align = [](size_t x){ return (x + 255) & ~(size_t)255; };
  size_t off = 0;
  size_t o_cent = off; off = align(off + (size_t)KIMG*CC*DD*4);
  size_t o_vidx = off; off = align(off + (size_t)KIMG*NTOK*4);
  size_t o_vcnt = off; off = align(off + (size_t)KIMG*4);
  size_t o_scal = off; off = align(off + (size_t)KIMG*CC*4*4);
  size_t o_h1   = off; off = align(off + (size_t)KIMG*CC*DD*4);
  size_t o_lbl  = off; off = align(off + (size_t)KIMG*NTOK*4);
  size_t o_fs   = off; off = align(off + (size_t)KIMG*TG*CC*DD*4);
  size_t o_sx   = off; off = align(off + (size_t)KIMG*NWV*CC*4);
  size_t o_sy   = off; off = align(off + (size_t)KIMG*NWV*CC*4);
  size_t o_cn   = off; off = align(off + (size_t)KIMG*NWV*CC*4);
  (void)ws_size;  // ~9.6 MB needed; prior rounds confirm ws_size is larger

  char* ws = (char*)d_ws;
  float* cent  = (float*)(ws + o_cent);
  int*   vidx  = (int*)  (ws + o_vidx);
  int*   vcnt  = (int*)  (ws + o_vcnt);
  float* scal  = (float*)(ws + o_scal);
  float* h1    = (float*)(ws + o_h1);
  int*   labels= (int*)  (ws + o_lbl);
  float* fsums = (float*)(ws + o_fs);
  float* sxg   = (float*)(ws + o_sx);
  float* syg   = (float*)(ws + o_sy);
  float* ocnt  = (float*)(ws + o_cn);

  compact_kernel<<<KIMG,256,0,stream>>>(mask, vidx, vcnt);
  init_kernel<<<KIMG,256,0,stream>>>(feat, boxes, Wp, bp, iidx, prawh, praww, cent);
  scalar_kernel<<<dim3(CC,KIMG),64,0,stream>>>(cent, Wp, bp, scal);
  for (int it=0; it<NITER; ++it){
    assign_kernel<<<dim3(GA,KIMG),512,0,stream>>>(feat, boxes, prawh, praww,
        cent, scal, vidx, vcnt, labels, sxg, syg, ocnt);
    sum_kernel<<<dim3(TG,3,KIMG),512,0,stream>>>(feat, vidx, vcnt, labels, fsums);
    update_kernel<<<KIMG*CC,256,0,stream>>>(fsums, sxg, syg, ocnt, Wp, bp, cent, scal);
  }
  mlp1_kernel<<<dim3(3,KIMG),256,0,stream>>>(cent, W1, b1, h1);
  mlp2_kernel<<<dim3(3,KIMG),256,0,stream>>>(h1, W2, b2, out);
}

// Round 11
// 1057.630 us; speedup vs baseline: 1.6933x; 1.6933x over previous
//
#include <hip/hip_runtime.h>
#include <hip/hip_bf16.h>
#include <math.h>

#define KIMG 8
#define HH 128
#define WW 128
#define NTOK (HH*WW)
#define DD 768
#define CC 10
#define NITER 5
#define GA 96           // fused blocks per image (768 total = 3/CU)
#define BW 4            // waves per fused block (256 threads)
#define NWV (GA*BW)     // 384 waves per image

// ---------- wave helpers ----------
__device__ __forceinline__ float rl63(float x){
  return __int_as_float(__builtin_amdgcn_readlane(__float_as_int(x), 63));
}
__device__ __forceinline__ float rfl_f(float x){
  return __int_as_float(__builtin_amdgcn_readfirstlane(__float_as_int(x)));
}
template<int CTRL,int RMASK>
__device__ __forceinline__ float dppadd(float x){
  // compiler-managed DPP (hazard-safe): mov_dpp + add
  int y = __builtin_amdgcn_update_dpp(0, __float_as_int(x), CTRL, RMASK, 0xf, true);
  return x + __int_as_float(y);
}
// full-wave sum; total lands in lane 63
__device__ __forceinline__ float wredsum(float x){
  x = dppadd<0x111,0xf>(x);
  x = dppadd<0x112,0xf>(x);
  x = dppadd<0x114,0xf>(x);
  x = dppadd<0x118,0xf>(x);
  x = dppadd<0x142,0xa>(x);
  x = dppadd<0x143,0xc>(x);
  return x;
}
__device__ __forceinline__ float read_dim_f(const int* p){
  int v = *p;
  if (v > 0 && v < (1<<20)) return (float)v;   // plausible integer
  return __int_as_float(v);                    // else float bits
}

union F4 { float4 v; float f[4]; };

// static-index accumulate of one token (12 dims/lane) into acc[c][0..11]
#define ADDC(c, x0, x1, x2) \
  { acc[c][0]+=x0.f[0]; acc[c][1]+=x0.f[1]; acc[c][2]+=x0.f[2]; acc[c][3]+=x0.f[3]; \
    acc[c][4]+=x1.f[0]; acc[c][5]+=x1.f[1]; acc[c][6]+=x1.f[2]; acc[c][7]+=x1.f[3]; \
    acc[c][8]+=x2.f[0]; acc[c][9]+=x2.f[1]; acc[c][10]+=x2.f[2]; acc[c][11]+=x2.f[3]; }
#define ACCUM(bl, x0, x1, x2) \
  switch(bl){ \
    case 0: ADDC(0,x0,x1,x2); break; case 1: ADDC(1,x0,x1,x2); break; \
    case 2: ADDC(2,x0,x1,x2); break; case 3: ADDC(3,x0,x1,x2); break; \
    case 4: ADDC(4,x0,x1,x2); break; case 5: ADDC(5,x0,x1,x2); break; \
    case 6: ADDC(6,x0,x1,x2); break; case 7: ADDC(7,x0,x1,x2); break; \
    case 8: ADDC(8,x0,x1,x2); break; default: ADDC(9,x0,x1,x2); break; }

// RMW a cluster range [CLO,CHI) of the block reduce buffer with this wave's acc
template<int CLO, int CHI>
__device__ __forceinline__ void red_range(float* B, float (*acc)[12], int lane, bool first){
  #pragma unroll
  for (int c = CLO; c < CHI; c++){
    #pragma unroll
    for (int j = 0; j < 3; j++){
      float* p = B + c*DD + j*256 + lane*4;
      F4 u;
      if (first){ u.f[0]=0.f; u.f[1]=0.f; u.f[2]=0.f; u.f[3]=0.f; }
      else      { u.v = *(const float4*)p; }
      u.f[0]+=acc[c][j*4+0]; u.f[1]+=acc[c][j*4+1];
      u.f[2]+=acc[c][j*4+2]; u.f[3]+=acc[c][j*4+3];
      *(float4*)p = u.v;
    }
  }
}

// ---------- 1. compact valid token indices (deterministic order) ----------
__global__ __launch_bounds__(256) void compact_kernel(const float* __restrict__ mask,
    int* __restrict__ vidx, int* __restrict__ vcnt){
  int k = blockIdx.x, tid = threadIdx.x;
  __shared__ int s[256];
  const float* mk = mask + (size_t)k*NTOK;
  int base = tid*64, c = 0;
  for (int j=0;j<64;j++) c += (mk[base+j] > 0.f) ? 1 : 0;
  s[tid] = c; __syncthreads();
  for (int st=1; st<256; st<<=1){
    int v = s[tid]; int u = (tid>=st) ? s[tid-st] : 0;
    __syncthreads(); s[tid] = v+u; __syncthreads();
  }
  int off = s[tid] - c;          // exclusive prefix
  if (tid==255) vcnt[k] = s[255];
  int* vk = vidx + (size_t)k*NTOK;
  for (int j=0;j<64;j++){ if (mk[base+j] > 0.f) vk[off++] = base+j; }
}

// ---------- 2. initial centroids = tokens[init_idx] ----------
__global__ __launch_bounds__(256) void init_kernel(const float* __restrict__ feat,
  const float* __restrict__ boxes, const float* __restrict__ Wp, const float* __restrict__ bp,
  const int* __restrict__ iidx, const int* __restrict__ prawh, const int* __restrict__ praww,
  float* __restrict__ cent){
  int k = blockIdx.x, tid = threadIdx.x;
  float top = boxes[k*4+0], lft = boxes[k*4+1], bot = boxes[k*4+2], rgt = boxes[k*4+3];
  float rh = read_dim_f(prawh), rw = read_dim_f(praww);
  float inv_rw = 1.f/(rw-1.f), inv_rh = 1.f/(rh-1.f);
  float xs = (rgt-lft)*(1.f/(float)WW), ys = (bot-top)*(1.f/(float)HH);
  for (int c=0;c<CC;c++){
    int tok = iidx[k*CC+c];
    int h = tok>>7, w = tok&127;
    float xg = fminf(fmaxf(((float)w*xs+lft)*inv_rw,0.f),1.f);
    float yg = fminf(fmaxf(((float)h*ys+top)*inv_rh,0.f),1.f);
    const float* fp = feat + ((size_t)k*NTOK + tok)*DD;
    float* cp = cent + ((size_t)k*CC + c)*DD;
    for (int d=tid; d<DD; d+=256)
      cp[d] = fp[d] + xg*Wp[d] + yg*Wp[DD+d] + bp[d];
  }
}

// ---------- 2b. initial per-cluster scalars ----------
__global__ __launch_bounds__(64) void scalar_kernel(const float* __restrict__ cent,
  const float* __restrict__ Wp, const float* __restrict__ bp, float* __restrict__ scal){
  int c = blockIdx.x, k = blockIdx.y, lane = threadIdx.x;
  const float* cp = cent + ((size_t)k*CC+c)*DD;
  float a0=0.f,a1=0.f,ab=0.f,an=0.f;
  #pragma unroll
  for (int j=0;j<12;j++){
    float cv = cp[j*64+lane];
    a0=fmaf(cv,Wp[j*64+lane],a0);
    a1=fmaf(cv,Wp[DD+j*64+lane],a1);
    ab=fmaf(cv,bp[j*64+lane],ab);
    an=fmaf(cv,cv,an);
  }
  a0=wredsum(a0); a1=wredsum(a1); ab=wredsum(ab); an=wredsum(an);
  if (lane==63){
    float* o = scal + ((size_t)k*CC+c)*4;
    o[0]=fmaf(-2.f,ab,an); o[1]=-2.f*a0; o[2]=-2.f*a1; o[3]=0.f;
  }
}

// ---------- 3. FUSED assign+sum: one feat pass, no atomics ----------
// Lane owns dims d = j*256 + lane*4 + m (3 coalesced b128 per token). Dots:
// 12 FMA/lane/cluster + DPP wave-reduce (independent pipelined chains). Label
// -> SGPR via readfirstlane -> static-index switch adds the ALREADY-LOADED
// registers into acc[10][12]. Cross-wave reduce: rotated disjoint cluster
// regions RMW into s_cent (dead after dot loop), 4 barriers, fixed order.
__global__ __launch_bounds__(256) void fused_kernel(
    const float* __restrict__ feat, const float* __restrict__ boxes,
    const int* __restrict__ prawh, const int* __restrict__ praww,
    const float* __restrict__ cent, const float* __restrict__ scal,
    const int* __restrict__ vidx, const int* __restrict__ vcnt,
    int* __restrict__ labels, float* __restrict__ fsums)
{
  int g = blockIdx.x, k = blockIdx.y;
  int tid = threadIdx.x, lane = tid & 63, wv = tid >> 6;
  __shared__ float s_cent[CC*DD];           // -2*cent; reused as reduce buffer
  const float* ck = cent + (size_t)k*CC*DD;
  for (int x=tid;x<CC*DD;x+=256) s_cent[x] = -2.f*ck[x];
  __syncthreads();

  float sA[CC], sW0[CC], sW1[CC];
  #pragma unroll
  for (int c=0;c<CC;c++){
    F4 sv; sv.v = *(const float4*)(scal + ((size_t)k*CC+c)*4);
    sA[c]=rfl_f(sv.f[0]); sW0[c]=rfl_f(sv.f[1]); sW1[c]=rfl_f(sv.f[2]);
  }

  float top=rfl_f(boxes[k*4+0]), lft=rfl_f(boxes[k*4+1]);
  float bot=rfl_f(boxes[k*4+2]), rgt=rfl_f(boxes[k*4+3]);
  float rh = read_dim_f(prawh), rw = read_dim_f(praww);
  float inv_rw = 1.f/(rw-1.f), inv_rh = 1.f/(rh-1.f);
  float xs = (rgt-lft)*(1.f/(float)WW), ys = (bot-top)*(1.f/(float)HH);

  int count = vcnt[k];
  int wid = g*BW + wv;                      // 0..NWV-1
  int cbeg = (int)(((long long)count * wid) / NWV);
  int cend = (int)(((long long)count * (wid+1)) / NWV);
  int mycnt = cend - cbeg;                  // ~28
  const int* vk = vidx + (size_t)k*NTOK;
  const float* featk = feat + (size_t)k*NTOK*DD;
  int* lk = labels + (size_t)k*NTOK;

  float acc[CC][12];
  #pragma unroll
  for (int c=0;c<CC;c++)
    #pragma unroll
    for (int j=0;j<12;j++) acc[c][j]=0.f;

  if (mycnt > 0){
    int vvt = vk[cbeg + min(lane, mycnt-1)];   // wave's token ids, lane-held

    for (int t=0; t<mycnt; t+=2){
      int tok0 = __builtin_amdgcn_readlane(vvt, t);
      int tok1 = __builtin_amdgcn_readlane(vvt, min(t+1, mycnt-1));
      const float* p0 = featk + (size_t)tok0*DD + lane*4;
      const float* p1 = featk + (size_t)tok1*DD + lane*4;
      F4 a0,a1,a2,b0,b1,b2;
      a0.v = *(const float4*)(p0);
      a1.v = *(const float4*)(p0+256);
      a2.v = *(const float4*)(p0+512);
      b0.v = *(const float4*)(p1);
      b1.v = *(const float4*)(p1+256);
      b2.v = *(const float4*)(p1+512);
      float xg0 = fminf(fmaxf(((float)(tok0&127)*xs+lft)*inv_rw,0.f),1.f);
      float yg0 = fminf(fmaxf(((float)(tok0>>7) *ys+top)*inv_rh,0.f),1.f);
      float xg1 = fminf(fmaxf(((float)(tok1&127)*xs+lft)*inv_rw,0.f),1.f);
      float yg1 = fminf(fmaxf(((float)(tok1>>7) *ys+top)*inv_rh,0.f),1.f);

      float best0=3.4e38f, best1=3.4e38f; int bv0=0, bv1=0;
      #pragma unroll
      for (int c=0;c<CC;c++){
        const float* cp = s_cent + c*DD + lane*4;
        F4 c0,c1,c2;
        c0.v = *(const float4*)(cp);
        c1.v = *(const float4*)(cp+256);
        c2.v = *(const float4*)(cp+512);
        float d0=0.f, d1=0.f;
        #pragma unroll
        for (int m=0;m<4;m++){
          d0 = fmaf(a0.f[m], c0.f[m], d0);  d1 = fmaf(b0.f[m], c0.f[m], d1);
          d0 = fmaf(a1.f[m], c1.f[m], d0);  d1 = fmaf(b1.f[m], c1.f[m], d1);
          d0 = fmaf(a2.f[m], c2.f[m], d0);  d1 = fmaf(b2.f[m], c2.f[m], d1);
        }
        d0 = wredsum(d0); d1 = wredsum(d1);
        float dd0 = rl63(d0), dd1 = rl63(d1);   // = -2*(t.c), uniform
        float sc0 = fmaf(xg0,sW0[c], fmaf(yg0,sW1[c], sA[c])) + dd0;
        float sc1 = fmaf(xg1,sW0[c], fmaf(yg1,sW1[c], sA[c])) + dd1;
        if (sc0 < best0){ best0=sc0; bv0=c; }
        if (sc1 < best1){ best1=sc1; bv1=c; }
      }
      int bl0 = __builtin_amdgcn_readfirstlane(bv0);
      int bl1 = __builtin_amdgcn_readfirstlane(bv1);

      if (lane==0) lk[cbeg+t] = bl0;
      ACCUM(bl0, a0, a1, a2);
      if (t+1 < mycnt){
        if (lane==0) lk[cbeg+t+1] = bl1;
        ACCUM(bl1, b0, b1, b2);
      }
    }
  }

  // cross-wave reduce into s_cent: rotated disjoint regions, fixed order
  __syncthreads();
  #pragma unroll
  for (int r=0; r<4; r++){
    int reg = (wv + r) & 3;
    bool first = (r == 0);
    switch(reg){
      case 0: red_range<0,3>(s_cent, acc, lane, first); break;
      case 1: red_range<3,5>(s_cent, acc, lane, first); break;
      case 2: red_range<5,8>(s_cent, acc, lane, first); break;
      default: red_range<8,10>(s_cent, acc, lane, first); break;
    }
    __syncthreads();
  }
  float* fo = fsums + ((size_t)(k*GA+g))*(CC*DD);
  for (int x=tid*4; x<CC*DD; x+=1024)
    *(float4*)(fo + x) = *(const float4*)(s_cent + x);
}

// ---------- 4. update: aux from labels + reduce GA partials + scal ----------
__global__ __launch_bounds__(256) void update_kernel(
  const float* __restrict__ fsums, const int* __restrict__ vidx,
  const int* __restrict__ vcnt, const int* __restrict__ labels,
  const float* __restrict__ boxes, const int* __restrict__ prawh,
  const int* __restrict__ praww, const float* __restrict__ Wp,
  const float* __restrict__ bp, float* __restrict__ cent, float* __restrict__ scal)
{
  int kc = blockIdx.x; int k = kc/CC, c = kc - k*CC;
  int tid = threadIdx.x, lane = tid & 63, wv = tid >> 6;
  __shared__ float rn[4], rx[4], ry[4];
  __shared__ float s0[4], s1[4], s2[4], s3[4];

  float top=boxes[k*4+0], lft=boxes[k*4+1], bot=boxes[k*4+2], rgt=boxes[k*4+3];
  float rh = read_dim_f(prawh), rw = read_dim_f(praww);
  float inv_rw = 1.f/(rw-1.f), inv_rh = 1.f/(rh-1.f);
  float xs = (rgt-lft)*(1.f/(float)WW), ys = (bot-top)*(1.f/(float)HH);

  int count = vcnt[k];
  const int* vk = vidx + (size_t)k*NTOK;
  const int* lk = labels + (size_t)k*NTOK;

  // aux scan over labels (same xg/yg math as fused kernel)
  float axc=0.f, axx=0.f, axy=0.f;
  for (int i=tid; i<count; i+=256){
    int lbl = lk[i];
    int tok = vk[i];
    float xg = fminf(fmaxf(((float)(tok&127)*xs+lft)*inv_rw,0.f),1.f);
    float yg = fminf(fmaxf(((float)(tok>>7) *ys+top)*inv_rh,0.f),1.f);
    bool m = (lbl == c);
    axc += m ? 1.f : 0.f;
    axx += m ? xg  : 0.f;
    axy += m ? yg  : 0.f;
  }
  axc=wredsum(axc); axx=wredsum(axx); axy=wredsum(axy);
  if (lane==63){ rn[wv]=axc; rx[wv]=axx; ry[wv]=axy; }
  __syncthreads();
  float n  = rn[0]+rn[1]+rn[2]+rn[3];
  float sx = rx[0]+rx[1]+rx[2]+rx[3];
  float sy = ry[0]+ry[1]+ry[2]+ry[3];
  bool upd = (n > 0.5f);

  float a0=0.f, a1=0.f, ab=0.f, an2=0.f;
  #pragma unroll
  for (int p=0;p<3;p++){
    int d = p*256 + tid;
    float s = 0.f;
    for (int g2=0; g2<GA; g2++)
      s += fsums[((size_t)(k*GA+g2))*(CC*DD) + c*DD + d];
    float w0 = Wp[d], w1 = Wp[DD+d], bb = bp[d];
    float val;
    if (upd) val = (s + sx*w0 + sy*w1 + n*bb) / n;     // factored posenc re-applied
    else     val = cent[(size_t)kc*DD + d];            // keep old centroid
    cent[(size_t)kc*DD + d] = val;
    a0  = fmaf(val, w0, a0);
    a1  = fmaf(val, w1, a1);
    ab  = fmaf(val, bb, ab);
    an2 = fmaf(val, val, an2);
  }
  a0=wredsum(a0); a1=wredsum(a1); ab=wredsum(ab); an2=wredsum(an2);
  if (lane==63){ s0[wv]=a0; s1[wv]=a1; s2[wv]=ab; s3[wv]=an2; }
  __syncthreads();
  if (tid==0){
    float A0 = s0[0]+s0[1]+s0[2]+s0[3];
    float A1 = s1[0]+s1[1]+s1[2]+s1[3];
    float AB = s2[0]+s2[1]+s2[2]+s2[3];
    float AN = s3[0]+s3[1]+s3[2]+s3[3];
    float* op = scal + (size_t)kc*4;
    op[0]=fmaf(-2.f,AB,AN); op[1]=-2.f*A0; op[2]=-2.f*A1; op[3]=0.f;
  }
}

// ---------- 5. MLP ----------
__global__ __launch_bounds__(256) void mlp1_kernel(const float* __restrict__ cent,
  const float* __restrict__ W1, const float* __restrict__ b1, float* __restrict__ h1)
{
  int k = blockIdx.y; int col = blockIdx.x*256 + threadIdx.x;
  __shared__ float srow[CC*DD];
  for (int x=threadIdx.x; x<CC*DD; x+=256) srow[x] = cent[(size_t)k*CC*DD + x];
  __syncthreads();
  float acc[CC];
  #pragma unroll
  for (int r=0;r<CC;r++) acc[r]=0.f;
  for (int dd=0; dd<DD; dd++){
    float wv = W1[(size_t)dd*DD + col];
    #pragma unroll
    for (int r=0;r<CC;r++) acc[r] = fmaf(srow[r*DD+dd], wv, acc[r]);
  }
  float bb = b1[col];
  #pragma unroll
  for (int r=0;r<CC;r++){
    float x = acc[r] + bb;
    h1[((size_t)k*CC+r)*DD + col] = 0.5f*x*(1.f+erff(x*0.70710678118654752440f));
  }
}

__global__ __launch_bounds__(256) void mlp2_kernel(const float* __restrict__ h1,
  const float* __restrict__ W2, const float* __restrict__ b2, float* __restrict__ out)
{
  int k = blockIdx.y; int col = blockIdx.x*256 + threadIdx.x;
  __shared__ float srow[CC*DD];
  for (int x=threadIdx.x; x<CC*DD; x+=256) srow[x] = h1[(size_t)k*CC*DD + x];
  __syncthreads();
  float acc[CC];
  #pragma unroll
  for (int r=0;r<CC;r++) acc[r]=0.f;
  for (int dd=0; dd<DD; dd++){
    float wv = W2[(size_t)dd*DD + col];
    #pragma unroll
    for (int r=0;r<CC;r++) acc[r] = fmaf(srow[r*DD+dd], wv, acc[r]);
  }
  float bb2 = b2[col];
  #pragma unroll
  for (int r=0;r<CC;r++) out[((size_t)k*CC+r)*DD + col] = acc[r] + bb2;
}

// ---------- launch ----------
extern "C" void kernel_launch(void* const* d_in, const int* in_sizes, int n_in,
                              void* d_out, int out_size, void* d_ws, size_t ws_size,
                              hipStream_t stream)
{
  const float* feat = (const float*)d_in[0];
  const float* mask = (const float*)d_in[1];
  const float* boxes= (const float*)d_in[2];
  const float* Wp   = (const float*)d_in[3];
  const float* bp   = (const float*)d_in[4];
  const float* W1   = (const float*)d_in[5];
  const float* b1   = (const float*)d_in[6];
  const float* W2   = (const float*)d_in[7];
  const float* b2   = (const float*)d_in[8];
  const int*   iidx = (const int*)d_in[9];
  const int*   prawh= (const int*)d_in[10];
  const int*   praww= (const int*)d_in[11];
  float* out = (float*)d_out;

  auto align = [](size_t x){ return (x + 255) & ~(size_t)255; };
  size_t off = 0;
  size_t o_cent = off; off = align(off + (size_t)KIMG*CC*DD*4);
  size_t o_vidx = off; off = align(off + (size_t)KIMG*NTOK*4);
  size_t o_vcnt = off; off = align(off + (size_t)KIMG*4);
  size_t o_scal = off; off = align(off + (size_t)KIMG*CC*4*4);
  size_t o_h1   = off; off = align(off + (size_t)KIMG*CC*DD*4);
  size_t o_lbl  = off; off = align(off + (size_t)KIMG*NTOK*4);
  size_t o_fs   = off; off = align(off + (size_t)KIMG*GA*CC*DD*4);
  (void)ws_size;  // ~25 MB needed; prior rounds confirm ws_size is larger

  char* ws = (char*)d_ws;
  float* cent  = (float*)(ws + o_cent);
  int*   vidx  = (int*)  (ws + o_vidx);
  int*   vcnt  = (int*)  (ws + o_vcnt);
  float* scal  = (float*)(ws + o_scal);
  float* h1    = (float*)(ws + o_h1);
  int*   labels= (int*)  (ws + o_lbl);
  float* fsums = (float*)(ws + o_fs);

  compact_kernel<<<KIMG,256,0,stream>>>(mask, vidx, vcnt);
  init_kernel<<<KIMG,256,0,stream>>>(feat, boxes, Wp, bp, iidx, prawh, praww, cent);
  scalar_kernel<<<dim3(CC,KIMG),64,0,stream>>>(cent, Wp, bp, scal);
  for (int it=0; it<NITER; ++it){
    fused_kernel<<<dim3(GA,KIMG),256,0,stream>>>(feat, boxes, prawh, praww,
        cent, scal, vidx, vcnt, labels, fsums);
    update_kernel<<<KIMG*CC,256,0,stream>>>(fsums, vidx, vcnt, labels,
        boxes, prawh, praww, Wp, bp, cent, scal);
  }
  mlp1_kernel<<<dim3(3,KIMG),256,0,stream>>>(cent, W1, b1, h1);
  mlp2_kernel<<<dim3(3,KIMG),256,0,stream>>>(h1, W2, b2, out);
}